// Round 1
// baseline (731.368 us; speedup 1.0000x reference)
//
#include <hip/hip_runtime.h>

// AliasFreeActivation fused kernel.
// x:(4,256,128,128) f32, bias:(256,), fup:(24,), fdn:(12,) -> out:(4,256,236,236) f32
//
// Derivation (per dim, both dims identical):
//  up (x4, 24 taps, pad 13/13 on dilated signal):  y[u] = sum_i f[u+10-4i]*x[i]
//    active taps: k = k0+4t, k0=(u+2)&3, t=0..5, i=(u+10-k)/4
//  leaky: a = (y>=0 ? y : 0.2y)*sqrt(2)
//  down (x2, 12 taps, pad 5/5): d[o] = sum_{k=0..11} g[k]*a[2o+6-k]
//  crop: out[j] = d[j+10], j in [0,236)
//
// Tile geometry (T=32 output pixels/dim):
//  d index range [oy0+10, oy0+41] -> 512-res range [2*oy0+15, 2*oy0+88] (74 wide)
//  -> input range [16*ty+1, 16*ty+24] (24 wide). All in-bounds for valid outputs;
//  speculative edge loads clamped (feed only masked-off outputs).

#define TS   32   // output tile
#define AW   74   // 512-res tile width = 2*TS+10
#define XW   24   // input tile width
#define XS   25   // xt LDS stride
#define T1S  75   // tmp1 stride
#define AS   75   // act stride
#define T2S  33   // tmp2 stride

__global__ __launch_bounds__(256) void afa_kernel(
    const float* __restrict__ x, const float* __restrict__ bias,
    const float* __restrict__ fup, const float* __restrict__ fdn,
    float* __restrict__ out)
{
    __shared__ float f_s[24];
    __shared__ float g_s[12];
    __shared__ float xt[XW * XS];    // 600
    __shared__ float t1[XW * T1S];   // 1800
    __shared__ float act[AW * AS];   // 5550
    __shared__ float t2[AW * T2S];   // 2442

    const int tid   = threadIdx.x;
    const int blk   = blockIdx.x;
    const int plane = blk >> 6;          // 1024 planes
    const int tile  = blk & 63;          // 8x8 tiles
    const int ty = tile >> 3, tx = tile & 7;
    const int c  = plane & 255;

    if (tid < 24) f_s[tid] = fup[tid];
    if (tid >= 32 && tid < 44) g_s[tid - 32] = fdn[tid - 32];

    const float b = bias[c];
    const int iy_base = 16 * ty + 1;
    const int ix_base = 16 * tx + 1;
    const float* xp = x + (size_t)plane * (128 * 128);

    // load 24x24 input tile (+bias), clamp speculative edge reads
    for (int e = tid; e < XW * XW; e += 256) {
        int r  = e / XW, cc = e - r * XW;
        int iy = min(iy_base + r, 127);
        int ix = min(ix_base + cc, 127);
        xt[r * XS + cc] = xp[iy * 128 + ix] + b;
    }
    __syncthreads();

    // step1: horizontal upsample -> t1[r][u], r in [0,24), u in [0,74)
    for (int e = tid; e < XW * AW; e += 256) {
        int r = e / AW, u = e - r * AW;
        int k0 = (u + 1) & 3;
        int base = ((u + 25 - k0) >> 2) - 1;
        float acc = 0.f;
        #pragma unroll
        for (int t = 0; t < 6; ++t)
            acc += f_s[k0 + 4 * t] * xt[r * XS + (base - t)];
        t1[r * T1S + u] = acc;
    }
    __syncthreads();

    // step2: vertical upsample + leakyReLU*sqrt2 -> act[v][u]
    for (int e = tid; e < AW * AW; e += 256) {
        int v = e / AW, u = e - v * AW;
        int k0 = (v + 1) & 3;
        int base = ((v + 25 - k0) >> 2) - 1;
        float acc = 0.f;
        #pragma unroll
        for (int t = 0; t < 6; ++t)
            acc += f_s[k0 + 4 * t] * t1[(base - t) * T1S + u];
        acc = (acc >= 0.f ? acc : 0.2f * acc) * 1.4142135623730951f;
        act[v * AS + u] = acc;
    }
    __syncthreads();

    // step3: horizontal downsample -> t2[v][o], o in [0,32)
    for (int e = tid; e < AW * TS; e += 256) {
        int v = e >> 5, o = e & 31;
        float acc = 0.f;
        #pragma unroll
        for (int k = 0; k < 12; ++k)
            acc += g_s[k] * act[v * AS + (2 * o + 11 - k)];
        t2[v * T2S + o] = acc;
    }
    __syncthreads();

    // step4: vertical downsample + crop-mask store
    const int oy0 = ty * TS, ox0 = tx * TS;
    float* op = out + (size_t)plane * (236 * 236);
    for (int e = tid; e < TS * TS; e += 256) {
        int oy_l = e >> 5, ox_l = e & 31;
        float acc = 0.f;
        #pragma unroll
        for (int k = 0; k < 12; ++k)
            acc += g_s[k] * t2[(2 * oy_l + 11 - k) * T2S + ox_l];
        int oy = oy0 + oy_l, ox = ox0 + ox_l;
        if (oy < 236 && ox < 236)
            op[oy * 236 + ox] = acc;
    }
}

extern "C" void kernel_launch(void* const* d_in, const int* in_sizes, int n_in,
                              void* d_out, int out_size, void* d_ws, size_t ws_size,
                              hipStream_t stream) {
    const float* x    = (const float*)d_in[0];
    const float* bias = (const float*)d_in[1];
    const float* fup  = (const float*)d_in[2];
    const float* fdn  = (const float*)d_in[3];
    float* out = (float*)d_out;

    // 1024 planes * 8x8 tiles
    dim3 grid(1024 * 64);
    dim3 block(256);
    afa_kernel<<<grid, block, 0, stream>>>(x, bias, fup, fdn, out);
}

// Round 2
// 305.796 us; speedup vs baseline: 2.3917x; 2.3917x over previous
//
#include <hip/hip_runtime.h>

// AliasFreeActivation fused kernel, register-tiled (round 2).
// x:(4,256,128,128) f32 -> out:(4,256,236,236) f32
//
// Math (verified round 1, passed):
//  A  h-up:   t1[r][u]  = sum_t f[k0+4t]*xt[r][base-t], k0=(u+1)&3 (local coords),
//             base=((u+25-k0)>>2)-1.  For u=4ut+du: window xt cols [ut,ut+6],
//             local base b(du)=5+((du+1)>>2).
//  B  v-up:   same vertically + leaky(x)*sqrt2. For v=8vt8+dv: window t1 rows
//             [2vt8, 2vt8+7], b(dv)=5+((dv+1)>>2).
//  C  h-down: t2[v][o] = sum_k g[k]*act[v][2o+11-k]. For o=4ot+o4: window act
//             cols [8ot, 8ot+17], local idx 2*o4+11-k.
//  D  v-down: out[oyl][col] = sum_k g[k]*t2[2oyl+11-k][col]; oyl=4v4+dv ->
//             window t2 rows [8v4, 8v4+17].
//
// LDS layout (words): xt 26x28 @0 | t1 26x76 @728 | act 80x76 @2704
//                     t2 76x33 @0 (aliases xt+t1, live after phase B)
// Garbage cells (t1 rows 24-25 / col 75, act rows 74-79 / cols 74-75, t2 rows
// 74-75) only feed outputs that are never read downstream.

typedef float f4 __attribute__((ext_vector_type(4)));

#define XTS     28
#define XT_OFF  0
#define T1S     76
#define T1_OFF  728
#define T2S     33
#define T2_OFF  0
#define ACTS    76
#define ACT_OFF 2704
#define LDSW    (2704 + 80 * 76)   // 8784 words = 35136 B

__global__ __launch_bounds__(256, 4) void afa_kernel(
    const float* __restrict__ x, const float* __restrict__ bias,
    const float* __restrict__ fup, const float* __restrict__ fdn,
    float* __restrict__ out)
{
    __shared__ __align__(16) float lds[LDSW];
    f4* lds4 = (f4*)lds;

    const int tid   = threadIdx.x;
    const int blk   = blockIdx.x;
    const int plane = blk >> 6;
    const int tile  = blk & 63;
    const int ty = tile >> 3, tx = tile & 7;
    const int c  = plane & 255;

    // filters into registers (uniform addresses -> scalar loads)
    float fr[24], gr[12];
    #pragma unroll
    for (int i = 0; i < 24; ++i) fr[i] = fup[i];
    #pragma unroll
    for (int i = 0; i < 12; ++i) gr[i] = fdn[i];

    const float b = bias[c];
    const int iy_base = 16 * ty + 1;
    const int ix_base = 16 * tx + 1;
    const float* xp = x + (size_t)plane * (128 * 128);

    // load 26x25 input tile (+bias); clamp speculative edge reads
    for (int e = tid; e < 26 * 25; e += 256) {
        int r  = e / 25, cc = e - r * 25;
        int iy = min(iy_base + r, 127);
        int ix = min(ix_base + cc, 127);
        lds[XT_OFF + r * XTS + cc] = xp[iy * 128 + ix] + b;
    }
    __syncthreads();

    // A: horizontal upsample -> t1 (26 rows x 76 cols), 4 cols/thread
    for (int task = tid; task < 26 * 19; task += 256) {
        int r = task / 19, ut = task - r * 19;
        float xw[7];
        #pragma unroll
        for (int m = 0; m < 7; ++m) xw[m] = lds[XT_OFF + r * XTS + ut + m];
        f4 res;
        #pragma unroll
        for (int du = 0; du < 4; ++du) {
            const int k0 = (du + 1) & 3;
            const int bb = 5 + ((du + 1) >> 2);
            float acc = 0.f;
            #pragma unroll
            for (int t = 0; t < 6; ++t) acc += fr[k0 + 4 * t] * xw[bb - t];
            res[du] = acc;
        }
        lds4[(T1_OFF >> 2) + r * 19 + ut] = res;
    }
    __syncthreads();

    // B: vertical upsample + leakyReLU*sqrt2 -> act (80 rows x 76 cols),
    //    8 rows x 4 cols per thread, all b128
    for (int task = tid; task < 190; task += 256) {
        int vt8 = task / 19, ut = task - vt8 * 19;
        f4 w[8];
        #pragma unroll
        for (int m = 0; m < 8; ++m)
            w[m] = lds4[(T1_OFF >> 2) + (2 * vt8 + m) * 19 + ut];
        #pragma unroll
        for (int dv = 0; dv < 8; ++dv) {
            const int k0 = (dv + 1) & 3;
            const int bb = 5 + ((dv + 1) >> 2);
            f4 acc = {0.f, 0.f, 0.f, 0.f};
            #pragma unroll
            for (int t = 0; t < 6; ++t) acc += fr[k0 + 4 * t] * w[bb - t];
            f4 r2;
            #pragma unroll
            for (int cc = 0; cc < 4; ++cc) {
                float v = acc[cc];
                r2[cc] = (v >= 0.f ? v : 0.2f * v) * 1.4142135623730951f;
            }
            lds4[(ACT_OFF >> 2) + (8 * vt8 + dv) * 19 + ut] = r2;
        }
    }
    __syncthreads();

    // C: horizontal downsample -> t2 (76 rows x 32 cols, stride 33), 4 cols/thread
    for (int task = tid; task < 76 * 8; task += 256) {
        int v = task >> 3, ot = task & 7;
        float aw[18];
        #pragma unroll
        for (int m = 0; m < 18; ++m) aw[m] = lds[ACT_OFF + v * ACTS + 8 * ot + m];
        #pragma unroll
        for (int o4 = 0; o4 < 4; ++o4) {
            float acc = 0.f;
            #pragma unroll
            for (int k = 0; k < 12; ++k) acc += gr[k] * aw[2 * o4 + 11 - k];
            lds[T2_OFF + v * T2S + 4 * ot + o4] = acc;
        }
    }
    __syncthreads();

    // D: vertical downsample, 4 rows x 1 col per thread, store to global
    {
        const int oy0 = ty * 32, ox0 = tx * 32;
        float* op = out + (size_t)plane * (236 * 236);
        const int v4 = tid >> 5, col = tid & 31;
        float cw[18];
        #pragma unroll
        for (int m = 0; m < 18; ++m)
            cw[m] = lds[T2_OFF + (8 * v4 + m) * T2S + col];
        const int ox = ox0 + col;
        #pragma unroll
        for (int dv = 0; dv < 4; ++dv) {
            float acc = 0.f;
            #pragma unroll
            for (int k = 0; k < 12; ++k) acc += gr[k] * cw[2 * dv + 11 - k];
            const int oy = oy0 + 4 * v4 + dv;
            if (oy < 236 && ox < 236) op[oy * 236 + ox] = acc;
        }
    }
}

extern "C" void kernel_launch(void* const* d_in, const int* in_sizes, int n_in,
                              void* d_out, int out_size, void* d_ws, size_t ws_size,
                              hipStream_t stream) {
    const float* x    = (const float*)d_in[0];
    const float* bias = (const float*)d_in[1];
    const float* fup  = (const float*)d_in[2];
    const float* fdn  = (const float*)d_in[3];
    float* out = (float*)d_out;

    dim3 grid(1024 * 64);
    dim3 block(256);
    afa_kernel<<<grid, block, 0, stream>>>(x, bias, fup, fdn, out);
}

// Round 3
// 284.495 us; speedup vs baseline: 2.5708x; 1.0749x over previous
//
#include <hip/hip_runtime.h>

// AliasFreeActivation fused kernel, round 3: vectorized C/D, conflict-free maps.
// x:(4,256,128,128) f32 -> out:(4,256,236,236) f32
//
// Math (verified rounds 1-2):
//  A  h-up:   t1[r][u] = sum_t f[k0+4t]*xw[bb-t], k0=(du+1)&3, bb=((du+25-k0)>>2)-1
//             for u=8ug+du, window xw = xt[r][2ug .. 2ug+7] (8 floats).
//  B  v-up:   same vertically + leaky*sqrt2; v=8vt8+dv, rows [2vt8,2vt8+7],
//             bb=5+((dv+1)>>2).
//  C  h-down: t2[v][o] = sum_k g[k]*act[v][2o+11-k]; o=8otg+i, window
//             act[v][16otg .. 16otg+25] read as 7xf4; STORE TRANSPOSED t2t[o][v].
//  D  v-down: out[4g+dv][ox] = sum_k g[k]*t2t[ox][8g+2dv+11-k]; window
//             t2t[ox][8g..8g+19] read as 5xf4.
//
// LDS (words): xt 26x28 @0 | t1 26x84 @728 | act 80x76 @2912  (8992 w = 35968 B)
//              t2t 32x76 @0 (aliases xt+t1, live after phase C)

typedef float f4 __attribute__((ext_vector_type(4)));

#define XTS     28
#define T1S4    21              // t1 stride in f4 (84 words)
#define T14     182             // t1 offset in f4 (728 words)
#define ACTS4   19              // act stride in f4 (76 words)
#define ACT4    728             // act offset in f4 (2912 words)
#define T2TS    76              // t2t stride in words
#define LDSW    8992

__global__ __launch_bounds__(256, 4) void afa_kernel(
    const float* __restrict__ x, const float* __restrict__ bias,
    const float* __restrict__ fup, const float* __restrict__ fdn,
    float* __restrict__ out)
{
    __shared__ __align__(16) float lds[LDSW];
    f4* lds4 = (f4*)lds;

    const int tid   = threadIdx.x;
    const int blk   = blockIdx.x;
    const int plane = blk >> 6;
    const int tile  = blk & 63;
    const int ty = tile >> 3, tx = tile & 7;

    float fr[24], gr[12];
    #pragma unroll
    for (int i = 0; i < 24; ++i) fr[i] = fup[i];
    #pragma unroll
    for (int i = 0; i < 12; ++i) gr[i] = fdn[i];

    const float b = bias[plane & 255];
    const int iy_base = 16 * ty + 1;
    const int ix_base = 16 * tx + 1;
    const float* xp = x + (size_t)plane * (128 * 128);

    // load 26x25 input tile (+bias); clamp speculative edge reads
    for (int e = tid; e < 26 * 25; e += 256) {
        int r  = e / 25, cc = e - r * 25;
        int iy = min(iy_base + r, 127);
        int ix = min(ix_base + cc, 127);
        lds[r * XTS + cc] = xp[iy * 128 + ix] + b;
    }
    __syncthreads();

    // A: horizontal upsample -> t1 (26 rows x 80 cols used), 8 cols/thread
    #pragma unroll
    for (int it = 0; it < 2; ++it) {
        int task = tid + 256 * it;
        if (task < 260) {
            int r = task / 10, ug = task - r * 10;
            float xw[8];
            #pragma unroll
            for (int m = 0; m < 8; ++m) xw[m] = lds[r * XTS + 2 * ug + m];
            f4 res0, res1;
            #pragma unroll
            for (int du = 0; du < 8; ++du) {
                const int k0 = (du + 1) & 3;
                const int bb = ((du + 25 - k0) >> 2) - 1;
                float acc = 0.f;
                #pragma unroll
                for (int t = 0; t < 6; ++t) acc += fr[k0 + 4 * t] * xw[bb - t];
                if (du < 4) res0[du] = acc; else res1[du - 4] = acc;
            }
            lds4[T14 + r * T1S4 + 2 * ug]     = res0;
            lds4[T14 + r * T1S4 + 2 * ug + 1] = res1;
        }
    }
    __syncthreads();

    // B: vertical upsample + leaky*sqrt2 -> act (80 x 76), 8 rows x 4 cols/thread
    if (tid < 190) {
        int vt8 = tid / 19, ut = tid - vt8 * 19;
        f4 w[8];
        #pragma unroll
        for (int m = 0; m < 8; ++m)
            w[m] = lds4[T14 + (2 * vt8 + m) * T1S4 + ut];
        #pragma unroll
        for (int dv = 0; dv < 8; ++dv) {
            const int k0 = (dv + 1) & 3;
            const int bb = 5 + ((dv + 1) >> 2);
            f4 acc = {0.f, 0.f, 0.f, 0.f};
            #pragma unroll
            for (int t = 0; t < 6; ++t) acc += fr[k0 + 4 * t] * w[bb - t];
            f4 r2;
            #pragma unroll
            for (int cc = 0; cc < 4; ++cc) {
                float v = acc[cc];
                r2[cc] = (v >= 0.f ? v : 0.2f * v) * 1.4142135623730951f;
            }
            lds4[ACT4 + (8 * vt8 + dv) * ACTS4 + ut] = r2;
        }
    }
    __syncthreads();

    // C: horizontal downsample -> t2t[o][v] (transposed), 8 o's per (v,otg) task
    {
        // batch 1: v = tid&63, otg = tid>>6 (lanes: consecutive v, same otg)
        int v = tid & 63, otg = tid >> 6;
        {
            union { f4 q[7]; float s[28]; } aw;
            #pragma unroll
            for (int j = 0; j < 7; ++j)
                aw.q[j] = lds4[ACT4 + v * ACTS4 + 4 * otg + j];
            #pragma unroll
            for (int i = 0; i < 8; ++i) {
                float acc = 0.f;
                #pragma unroll
                for (int k = 0; k < 12; ++k) acc += gr[k] * aw.s[2 * i + 11 - k];
                lds[(8 * otg + i) * T2TS + v] = acc;
            }
        }
        // batch 2: rows 64..75
        if (tid < 64) {
            int otg2 = tid >> 4, vr = tid & 15;
            if (vr < 12) {
                int v2 = 64 + vr;
                union { f4 q[7]; float s[28]; } aw;
                #pragma unroll
                for (int j = 0; j < 7; ++j)
                    aw.q[j] = lds4[ACT4 + v2 * ACTS4 + 4 * otg2 + j];
                #pragma unroll
                for (int i = 0; i < 8; ++i) {
                    float acc = 0.f;
                    #pragma unroll
                    for (int k = 0; k < 12; ++k) acc += gr[k] * aw.s[2 * i + 11 - k];
                    lds[(8 * otg2 + i) * T2TS + v2] = acc;
                }
            }
        }
    }
    __syncthreads();

    // D: vertical downsample from t2t, 4 rows x 1 col/thread, store to global
    {
        const int oy0 = ty * 32, ox0 = tx * 32;
        float* op = out + (size_t)plane * (236 * 236);
        const int ox = tid & 31, g = tid >> 5;
        union { f4 q[5]; float s[20]; } cw;
        #pragma unroll
        for (int j = 0; j < 5; ++j)
            cw.q[j] = lds4[ox * ACTS4 + 2 * g + j];   // word ox*76 + 8g + 4j
        const int oxg = ox0 + ox;
        #pragma unroll
        for (int dv = 0; dv < 4; ++dv) {
            float acc = 0.f;
            #pragma unroll
            for (int k = 0; k < 12; ++k) acc += gr[k] * cw.s[2 * dv + 11 - k];
            const int oy = oy0 + 4 * g + dv;
            if (oy < 236 && oxg < 236) op[oy * 236 + oxg] = acc;
        }
    }
}

extern "C" void kernel_launch(void* const* d_in, const int* in_sizes, int n_in,
                              void* d_out, int out_size, void* d_ws, size_t ws_size,
                              hipStream_t stream) {
    const float* x    = (const float*)d_in[0];
    const float* bias = (const float*)d_in[1];
    const float* fup  = (const float*)d_in[2];
    const float* fdn  = (const float*)d_in[3];
    float* out = (float*)d_out;

    dim3 grid(1024 * 64);
    dim3 block(256);
    afa_kernel<<<grid, block, 0, stream>>>(x, bias, fup, fdn, out);
}